// Round 1
// baseline (849.479 us; speedup 1.0000x reference)
//
#include <hip/hip_runtime.h>
#include <hip/hip_bf16.h>
#include <cstdint>
#include <cstddef>

#define N_NODES 50000
#define FDIM 512

typedef __bf16 bf16_t;
typedef bf16_t bf16x8 __attribute__((ext_vector_type(8)));
typedef float f32x4 __attribute__((ext_vector_type(4)));

__device__ __forceinline__ unsigned short f2bf(float f) {
  union { float f; uint32_t u; } c; c.f = f;
  uint32_t u = c.u;
  uint32_t r = (u + 0x7fffu + ((u >> 16) & 1u)) >> 16;  // RNE
  return (unsigned short)r;
}

__device__ __forceinline__ void async16(const void* g, void* l) {
  __builtin_amdgcn_global_load_lds((const __attribute__((address_space(1))) void*)g,
                                   (__attribute__((address_space(3))) void*)l, 16, 0, 0);
}

// ---------------- CSR build ----------------
__global__ void count_edges(const int* __restrict__ d1, const int* __restrict__ d2,
                            int* __restrict__ c1, int* __restrict__ c2, int E1, int E2) {
  int e = blockIdx.x * 256 + threadIdx.x;
  if (e < E1) atomicAdd(&c1[d1[e]], 1);
  if (e < E2) atomicAdd(&c2[d2[e]], 1);
}

// single-block exclusive scan over n counts -> rowptr, plus dinv = rsqrt(cnt+1)
__global__ __launch_bounds__(1024) void scan_build(const int* __restrict__ cnt,
                                                   int* __restrict__ rowptr,
                                                   float* __restrict__ dinv, int n) {
  __shared__ int part[1024];
  const int t = threadIdx.x;
  const int per = (n + 1023) / 1024;
  const int lo = t * per;
  const int hi = (lo + per < n) ? lo + per : n;
  int s = 0;
  for (int i = lo; i < hi; i++) s += cnt[i];
  part[t] = s;
  __syncthreads();
  for (int off = 1; off < 1024; off <<= 1) {
    int v = (t >= off) ? part[t - off] : 0;
    __syncthreads();
    part[t] += v;
    __syncthreads();
  }
  int pre = (t == 0) ? 0 : part[t - 1];
  for (int i = lo; i < hi; i++) {
    int c = cnt[i];
    rowptr[i] = pre;
    dinv[i] = rsqrtf((float)c + 1.0f);  // deg includes self-loop
    pre += c;
  }
  if (t == 1023) rowptr[n] = pre;
}

__global__ void fill_csr(const int* __restrict__ s1, const int* __restrict__ d1,
                         const int* __restrict__ rp1, int* __restrict__ cur1,
                         const float* __restrict__ dv1, int* __restrict__ c1s,
                         float* __restrict__ c1w, int E1,
                         const int* __restrict__ s2, const int* __restrict__ d2,
                         const int* __restrict__ rp2, int* __restrict__ cur2,
                         const float* __restrict__ dv2, int* __restrict__ c2s,
                         float* __restrict__ c2w, int E2) {
  int e = blockIdx.x * 256 + threadIdx.x;
  if (e < E1) {
    int s = s1[e], d = d1[e];
    int pos = rp1[d] + atomicAdd(&cur1[d], 1);
    c1s[pos] = s; c1w[pos] = dv1[s];
  }
  if (e < E2) {
    int s = s2[e], d = d2[e];
    int pos = rp2[d] + atomicAdd(&cur2[d], 1);
    c2s[pos] = s; c2w[pos] = dv2[s];
  }
}

// ---------------- dtype converts ----------------
__global__ void cvt_x(const float4* __restrict__ X, ushort4* __restrict__ out, int n4) {
  int stride = gridDim.x * 256;
  for (int i = blockIdx.x * 256 + threadIdx.x; i < n4; i += stride) {
    float4 v = X[i];
    ushort4 o;
    o.x = f2bf(v.x); o.y = f2bf(v.y); o.z = f2bf(v.z); o.w = f2bf(v.w);
    out[i] = o;
  }
}

// WcatT[n][k] (n<256 -> W10 col n, else W20 col n-256), W21T[n][k] = W21[k][n]
__global__ void cvt_w(const float* __restrict__ W10, const float* __restrict__ W20,
                      const float* __restrict__ W21, unsigned short* __restrict__ WcatT,
                      unsigned short* __restrict__ W21T) {
  int j = blockIdx.x * 256 + threadIdx.x;
  const int T1 = 320 * 512;
  if (j < T1) {
    int n = j >> 9, k = j & 511;
    float v = (n < 256) ? W10[k * 256 + n] : W20[k * 64 + (n - 256)];
    WcatT[j] = f2bf(v);
  } else {
    int j2 = j - T1;
    if (j2 < 256 * 64) {
      int n = j2 >> 6, k = j2 & 63;
      W21T[j2] = f2bf(W21[k * 256 + n]);
    }
  }
}

// ---------------- bf16 MFMA GEMM: C[M,N] = A[M,KTOT] * B^T[N,KTOT] ----------------
// tile 128(M) x 64(N), BK=64, 256 threads (4 waves), wave = 32(M) x 64(N)
// MODE 0: cols<256 -> out1 (stride 256), cols>=256 -> out2 (stride 64, col-256)
// MODE 1: out1 only (stride 256)
template <int KTOT, int MODE>
__global__ __launch_bounds__(256) void gemm_bt(const unsigned short* __restrict__ A,
                                               const unsigned short* __restrict__ B,
                                               float* __restrict__ out1,
                                               float* __restrict__ out2, int M) {
  __shared__ unsigned short As[128 * 64];
  __shared__ unsigned short Bs[64 * 64];
  const int tid = threadIdx.x;
  const int w = tid >> 6, lane = tid & 63;
  const int row0 = blockIdx.x * 128;
  const int n0 = blockIdx.y * 64;
  const int lr = lane >> 3;          // row-within-8 for staging
  const int lc8 = (lane & 7) * 8;    // k-offset for staging (8 bf16 = 16B)
  const int mlane = lane & 15, q = lane >> 4;

  f32x4 acc[2][4];
#pragma unroll
  for (int mi = 0; mi < 2; mi++)
#pragma unroll
    for (int ni = 0; ni < 4; ni++) {
      f32x4 z = {0.f, 0.f, 0.f, 0.f};
      acc[mi][ni] = z;
    }

  for (int k0 = 0; k0 < KTOT; k0 += 64) {
    __syncthreads();  // previous iter's LDS reads done
#pragma unroll
    for (int i = 0; i < 4; i++) {
      int gr = row0 + i * 32 + w * 8 + lr;
      if (gr > M - 1) gr = M - 1;  // clamp; stores masked in epilogue
      async16(A + (size_t)gr * KTOT + k0 + lc8, &As[(i * 256 + w * 64) * 8]);
    }
#pragma unroll
    for (int i = 0; i < 2; i++) {
      int n = i * 32 + w * 8 + lr;
      async16(B + (size_t)(n0 + n) * KTOT + k0 + lc8, &Bs[(i * 256 + w * 64) * 8]);
    }
    __syncthreads();  // drains global_load_lds (vmcnt) + barrier
#pragma unroll
    for (int kk = 0; kk < 2; kk++) {
      bf16x8 af[2], bfr[4];
#pragma unroll
      for (int mi = 0; mi < 2; mi++)
        af[mi] = *(const bf16x8*)&As[(w * 32 + mi * 16 + mlane) * 64 + kk * 32 + q * 8];
#pragma unroll
      for (int ni = 0; ni < 4; ni++)
        bfr[ni] = *(const bf16x8*)&Bs[(ni * 16 + mlane) * 64 + kk * 32 + q * 8];
#pragma unroll
      for (int mi = 0; mi < 2; mi++)
#pragma unroll
        for (int ni = 0; ni < 4; ni++)
          acc[mi][ni] = __builtin_amdgcn_mfma_f32_16x16x32_bf16(af[mi], bfr[ni], acc[mi][ni], 0, 0, 0);
    }
  }

#pragma unroll
  for (int mi = 0; mi < 2; mi++)
#pragma unroll
    for (int ni = 0; ni < 4; ni++) {
      int c = n0 + ni * 16 + mlane;
#pragma unroll
      for (int rg = 0; rg < 4; rg++) {
        int r = row0 + w * 32 + mi * 16 + q * 4 + rg;  // C/D: col=lane&15, row=(lane>>4)*4+reg
        if (r < M) {
          float v = acc[mi][ni][rg];
          if (MODE == 0) {
            if (c < 256) out1[(size_t)r * 256 + c] = v;
            else out2[(size_t)r * 64 + (c - 256)] = v;
          } else {
            out1[(size_t)r * 256 + c] = v;
          }
        }
      }
    }
}

// ---------------- propagation (gather-CSR) ----------------
// out[i,f] = relu( dinv[i]*( sum_e w[e]*H[src,f] + dinv[i]*H[i,f] ) + bias[f] )
__global__ __launch_bounds__(256) void prop256(const float* __restrict__ H,
                                               const int* __restrict__ rp,
                                               const int* __restrict__ cs,
                                               const float* __restrict__ cw,
                                               const float* __restrict__ dinv,
                                               const float* __restrict__ bias,
                                               float* __restrict__ out, int n) {
  const int i = blockIdx.x;
  const int f = threadIdx.x;
  const float di = dinv[i];
  float acc = di * H[(size_t)i * 256 + f];
  const int e1 = rp[i + 1];
#pragma unroll 4
  for (int e = rp[i]; e < e1; e++)
    acc += cw[e] * H[(size_t)cs[e] * 256 + f];
  out[(size_t)i * 256 + f] = fmaxf(di * acc + bias[f], 0.f);
}

// 64-dim, +bias, no relu (layer-2 output h2)
__global__ __launch_bounds__(256) void prop64_f32(const float* __restrict__ H,
                                                  const int* __restrict__ rp,
                                                  const int* __restrict__ cs,
                                                  const float* __restrict__ cw,
                                                  const float* __restrict__ dinv,
                                                  const float* __restrict__ bias,
                                                  float* __restrict__ out, int n) {
  const int i = blockIdx.x * 4 + (threadIdx.x >> 6);
  const int f = threadIdx.x & 63;
  if (i >= n) return;
  const float di = dinv[i];
  float acc = di * H[(size_t)i * 64 + f];
  const int e1 = rp[i + 1];
#pragma unroll 4
  for (int e = rp[i]; e < e1; e++)
    acc += cw[e] * H[(size_t)cs[e] * 64 + f];
  out[(size_t)i * 64 + f] = di * acc + bias[f];
}

// 64-dim, raw propagate, bf16 output (q2 = prop2(h2), feeds MFMA GEMM)
__global__ __launch_bounds__(256) void prop64_bf16(const float* __restrict__ H,
                                                   const int* __restrict__ rp,
                                                   const int* __restrict__ cs,
                                                   const float* __restrict__ cw,
                                                   const float* __restrict__ dinv,
                                                   unsigned short* __restrict__ out, int n) {
  const int i = blockIdx.x * 4 + (threadIdx.x >> 6);
  const int f = threadIdx.x & 63;
  if (i >= n) return;
  const float di = dinv[i];
  float acc = di * H[(size_t)i * 64 + f];
  const int e1 = rp[i + 1];
#pragma unroll 4
  for (int e = rp[i]; e < e1; e++)
    acc += cw[e] * H[(size_t)cs[e] * 64 + f];
  out[(size_t)i * 64 + f] = f2bf(di * acc);
}

// ---------------- fused tail: h = relu(h3+b21)+h1 ; out = h @ Wfc + bfc ----------------
__global__ __launch_bounds__(256) void final_k(const float* __restrict__ h1,
                                               const float* __restrict__ h3,
                                               const float* __restrict__ b21,
                                               const float* __restrict__ Wfc,
                                               const float* __restrict__ bfc,
                                               float* __restrict__ out, int M) {
  __shared__ float hs[16][260];  // +4 pad: bank-spread, keeps 16B alignment
  __shared__ float wt[16][260];  // WfcT[c][k]
  __shared__ float bs[16];
  const int t = threadIdx.x;
  for (int j = t; j < 4096; j += 256) { int k = j >> 4, c = j & 15; wt[c][k] = Wfc[j]; }
  if (t < 16) bs[t] = bfc[t];
  const float bb = b21[t];
  const int node0 = blockIdx.x * 16;
#pragma unroll
  for (int nl = 0; nl < 16; nl++) {
    int i = node0 + nl;
    float v = 0.f;
    if (i < M) {
      size_t o = (size_t)i * 256 + t;
      v = fmaxf(h3[o] + bb, 0.f) + h1[o];
    }
    hs[nl][t] = v;
  }
  __syncthreads();
  const int nl = t >> 4, c = t & 15;
  const int i = node0 + nl;
  if (i >= M) return;
  const float4* hp = (const float4*)&hs[nl][0];
  const float4* wp = (const float4*)&wt[c][0];
  float s = bs[c];
#pragma unroll 8
  for (int k4 = 0; k4 < 64; k4++) {
    float4 a = hp[k4], b = wp[k4];
    s += a.x * b.x + a.y * b.y + a.z * b.z + a.w * b.w;
  }
  out[(size_t)i * 16 + c] = s;
}

// ---------------- launch ----------------
extern "C" void kernel_launch(void* const* d_in, const int* in_sizes, int n_in,
                              void* d_out, int out_size, void* d_ws, size_t ws_size,
                              hipStream_t stream) {
  const float* X   = (const float*)d_in[0];
  const int*   ei1 = (const int*)d_in[1];
  const int*   ei2 = (const int*)d_in[2];
  const float* W10 = (const float*)d_in[3];
  const float* b10 = (const float*)d_in[4];
  const float* W20 = (const float*)d_in[5];
  const float* b20 = (const float*)d_in[6];
  const float* W21 = (const float*)d_in[7];
  const float* b21 = (const float*)d_in[8];
  const float* Wfc = (const float*)d_in[9];
  const float* bfc = (const float*)d_in[10];
  float* out = (float*)d_out;

  const int N = N_NODES;
  const int E1 = in_sizes[1] / 2, E2 = in_sizes[2] / 2;
  const int* src1 = ei1; const int* dst1 = ei1 + E1;
  const int* src2 = ei2; const int* dst2 = ei2 + E2;
  const int Emax = (E1 > E2) ? E1 : E2;

  char* p = (char*)d_ws;
  auto alloc = [&](size_t b) { char* r = p; p += (b + 255) & ~(size_t)255; return (void*)r; };
  int* cnts = (int*)alloc((size_t)4 * N * 4);  // cnt1,cnt2,cur1,cur2 adjacent (one memset)
  int *cnt1 = cnts, *cnt2 = cnts + N, *cur1 = cnts + 2 * N, *cur2 = cnts + 3 * N;
  int* rp1 = (int*)alloc((size_t)(N + 1) * 4);
  int* rp2 = (int*)alloc((size_t)(N + 1) * 4);
  float* dinv1 = (float*)alloc((size_t)N * 4);
  float* dinv2 = (float*)alloc((size_t)N * 4);
  int*   csr1s = (int*)alloc((size_t)E1 * 4);
  float* csr1w = (float*)alloc((size_t)E1 * 4);
  int*   csr2s = (int*)alloc((size_t)E2 * 4);
  float* csr2w = (float*)alloc((size_t)E2 * 4);
  unsigned short* WcatT = (unsigned short*)alloc(320 * 512 * 2);
  unsigned short* W21T  = (unsigned short*)alloc(256 * 64 * 2);
  unsigned short* Xb = (unsigned short*)alloc((size_t)N * 512 * 2);  // reused as h1 (N*256 f32)
  float* h1 = (float*)Xb;
  float* Xh1 = (float*)alloc((size_t)N * 256 * 4);  // reused as h3pre
  float* h3 = Xh1;
  float* Xh2 = (float*)alloc((size_t)N * 64 * 4);   // reused as q2 bf16
  unsigned short* q2b = (unsigned short*)Xh2;
  float* h2 = (float*)alloc((size_t)N * 64 * 4);

  hipMemsetAsync(cnts, 0, (size_t)4 * N * 4, stream);

  const int eblk = (Emax + 255) / 256;
  count_edges<<<dim3(eblk), 256, 0, stream>>>(dst1, dst2, cnt1, cnt2, E1, E2);
  scan_build<<<dim3(1), 1024, 0, stream>>>(cnt1, rp1, dinv1, N);
  scan_build<<<dim3(1), 1024, 0, stream>>>(cnt2, rp2, dinv2, N);
  fill_csr<<<dim3(eblk), 256, 0, stream>>>(src1, dst1, rp1, cur1, dinv1, csr1s, csr1w, E1,
                                           src2, dst2, rp2, cur2, dinv2, csr2s, csr2w, E2);
  cvt_x<<<dim3(4096), 256, 0, stream>>>((const float4*)X, (ushort4*)Xb, N * FDIM / 4);
  cvt_w<<<dim3((320 * 512 + 256 * 64 + 255) / 256), 256, 0, stream>>>(W10, W20, W21, WcatT, W21T);
  // Xh1 = x@W10, Xh2 = x@W20 (fused: x @ [W10|W20])
  gemm_bt<512, 0><<<dim3((N + 127) / 128, 5), 256, 0, stream>>>(Xb, WcatT, Xh1, Xh2, N);
  // h1 = relu(prop1(Xh1) + b10)   (overwrites Xb)
  prop256<<<dim3(N), 256, 0, stream>>>(Xh1, rp1, csr1s, csr1w, dinv1, b10, h1, N);
  // h2 = prop2(Xh2) + b20
  prop64_f32<<<dim3((N + 3) / 4), 256, 0, stream>>>(Xh2, rp2, csr2s, csr2w, dinv2, b20, h2, N);
  // q2 = prop2(h2)  -> bf16  (overwrites Xh2)
  prop64_bf16<<<dim3((N + 3) / 4), 256, 0, stream>>>(h2, rp2, csr2s, csr2w, dinv2, q2b, N);
  // h3pre = q2 @ W21  (prop/transform commute; overwrites Xh1)
  gemm_bt<64, 1><<<dim3((N + 127) / 128, 4), 256, 0, stream>>>(q2b, W21T, h3, nullptr, N);
  // out = (relu(h3+b21)+h1) @ Wfc + bfc
  final_k<<<dim3((N + 15) / 16), 256, 0, stream>>>(h1, h3, b21, Wfc, bfc, out, N);
}

// Round 3
// 675.359 us; speedup vs baseline: 1.2578x; 1.2578x over previous
//
#include <hip/hip_runtime.h>
#include <hip/hip_bf16.h>
#include <cstdint>
#include <cstddef>

#define N_NODES 50000
#define FDIM 512

typedef __bf16 bf16_t;
typedef bf16_t bf16x8 __attribute__((ext_vector_type(8)));
typedef float f32x4 __attribute__((ext_vector_type(4)));

__device__ __forceinline__ unsigned short f2bf(float f) {
  union { float f; uint32_t u; } c; c.f = f;
  uint32_t u = c.u;
  uint32_t r = (u + 0x7fffu + ((u >> 16) & 1u)) >> 16;  // RNE
  return (unsigned short)r;
}
__device__ __forceinline__ float bf2f(unsigned short u) {
  union { uint32_t i; float f; } c; c.i = (uint32_t)u << 16; return c.f;
}
__device__ __forceinline__ float4 ld_bf4(const unsigned short* p) {
  ushort4 u = *(const ushort4*)p;
  float4 r; r.x = bf2f(u.x); r.y = bf2f(u.y); r.z = bf2f(u.z); r.w = bf2f(u.w);
  return r;
}
__device__ __forceinline__ void async16(const void* g, void* l) {
  __builtin_amdgcn_global_load_lds((const __attribute__((address_space(1))) void*)g,
                                   (__attribute__((address_space(3))) void*)l, 16, 0, 0);
}

// ---------------- CSR build ----------------
__global__ void count_edges(const int* __restrict__ d1, const int* __restrict__ d2,
                            int* __restrict__ c1, int* __restrict__ c2, int E1, int E2) {
  int e = blockIdx.x * 256 + threadIdx.x;
  if (e < E1) atomicAdd(&c1[d1[e]], 1);
  if (e < E2) atomicAdd(&c2[d2[e]], 1);
}

// grid=2: block g scans graph g's counts -> rowptr, cur(=rowptr copy), dinv
__global__ __launch_bounds__(1024) void scan_build2(const int* __restrict__ cnt1,
                                                    int* __restrict__ rp1, int* __restrict__ cur1,
                                                    float* __restrict__ dv1,
                                                    const int* __restrict__ cnt2,
                                                    int* __restrict__ rp2, int* __restrict__ cur2,
                                                    float* __restrict__ dv2, int n) {
  const int* cnt = blockIdx.x ? cnt2 : cnt1;
  int* rowptr = blockIdx.x ? rp2 : rp1;
  int* cur = blockIdx.x ? cur2 : cur1;
  float* dinv = blockIdx.x ? dv2 : dv1;
  __shared__ int part[1024];
  const int t = threadIdx.x;
  const int per = (n + 1023) / 1024;
  const int lo = t * per;
  const int hi = (lo + per < n) ? lo + per : n;
  int s = 0;
  for (int i = lo; i < hi; i++) s += cnt[i];
  part[t] = s;
  __syncthreads();
  for (int off = 1; off < 1024; off <<= 1) {
    int v = (t >= off) ? part[t - off] : 0;
    __syncthreads();
    part[t] += v;
    __syncthreads();
  }
  int pre = (t == 0) ? 0 : part[t - 1];
  for (int i = lo; i < hi; i++) {
    int c = cnt[i];
    rowptr[i] = pre;
    cur[i] = pre;
    dinv[i] = rsqrtf((float)c + 1.0f);  // deg includes self-loop
    pre += c;
  }
  if (t == 1023) rowptr[n] = pre;
}

__global__ void fill_csr(const int* __restrict__ s1, const int* __restrict__ d1,
                         int* __restrict__ cur1, const float* __restrict__ dv1,
                         int* __restrict__ c1s, float* __restrict__ c1w, int E1,
                         const int* __restrict__ s2, const int* __restrict__ d2,
                         int* __restrict__ cur2, const float* __restrict__ dv2,
                         int* __restrict__ c2s, float* __restrict__ c2w, int E2) {
  int e = blockIdx.x * 256 + threadIdx.x;
  if (e < E1) {
    int s = s1[e];
    int pos = atomicAdd(&cur1[d1[e]], 1);
    c1s[pos] = s; c1w[pos] = dv1[s];
  }
  if (e < E2) {
    int s = s2[e];
    int pos = atomicAdd(&cur2[d2[e]], 1);
    c2s[pos] = s; c2w[pos] = dv2[s];
  }
}

// ---------------- dtype converts ----------------
__global__ void cvt_x(const float4* __restrict__ X, ushort4* __restrict__ out, int n4) {
  int stride = gridDim.x * 256;
  for (int i = blockIdx.x * 256 + threadIdx.x; i < n4; i += stride) {
    float4 v = X[i];
    ushort4 o;
    o.x = f2bf(v.x); o.y = f2bf(v.y); o.z = f2bf(v.z); o.w = f2bf(v.w);
    out[i] = o;
  }
}

// WcatT[384][512]: n<256 -> W10 col n; 256<=n<320 -> W20 col n-256; else 0 (pad)
// W21T[256][64]: W21 transposed
__global__ void cvt_w(const float* __restrict__ W10, const float* __restrict__ W20,
                      const float* __restrict__ W21, unsigned short* __restrict__ WcatT,
                      unsigned short* __restrict__ W21T) {
  int j = blockIdx.x * 256 + threadIdx.x;
  const int T1 = 384 * 512;
  if (j < T1) {
    int n = j >> 9, k = j & 511;
    float v = (n < 256) ? W10[k * 256 + n] : ((n < 320) ? W20[k * 64 + (n - 256)] : 0.f);
    WcatT[j] = f2bf(v);
  } else {
    int j2 = j - T1;
    if (j2 < 256 * 64) {
      int n = j2 >> 6, k = j2 & 63;
      W21T[j2] = f2bf(W21[k * 256 + n]);
    }
  }
}

// ---------------- bf16 MFMA GEMM: C[M,N] = A[M,KTOT] * B^T[N,KTOT] ----------------
// m97 structure: tile 128(M) x 128(N), BK=64, 256 threads (4 waves), wave = 64x64, 4x4 acc.
// SPLIT=1: bf16 dual-output (c<256 -> o1 stride 256; 256<=c<NLIM -> o2 stride 64)
// SPLIT=0: f32 single output (stride 256)
template <int KTOT, int SPLIT>
__global__ __launch_bounds__(256) void gemm_bt(const unsigned short* __restrict__ A,
                                               const unsigned short* __restrict__ B,
                                               void* __restrict__ o1, void* __restrict__ o2,
                                               int M, int NLIM) {
  __shared__ unsigned short As[128 * 64];
  __shared__ unsigned short Bs[128 * 64];
  const int tid = threadIdx.x;
  const int w = tid >> 6, lane = tid & 63;
  const int row0 = blockIdx.x * 128;
  const int n0 = blockIdx.y * 128;
  const int wm = w >> 1, wn = w & 1;          // wave 2x2 grid, each 64(M)x64(N)
  const int lr = lane >> 3, lc8 = (lane & 7) * 8;
  const int mlane = lane & 15, q = lane >> 4;

  f32x4 acc[4][4];
#pragma unroll
  for (int mi = 0; mi < 4; mi++)
#pragma unroll
    for (int ni = 0; ni < 4; ni++) {
      f32x4 z = {0.f, 0.f, 0.f, 0.f};
      acc[mi][ni] = z;
    }

  for (int k0 = 0; k0 < KTOT; k0 += 64) {
    __syncthreads();
#pragma unroll
    for (int i = 0; i < 4; i++) {
      int gr = row0 + i * 32 + w * 8 + lr;
      if (gr > M - 1) gr = M - 1;  // clamp; stores masked in epilogue
      async16(A + (size_t)gr * KTOT + k0 + lc8, &As[(i * 32 + w * 8) * 64]);
    }
#pragma unroll
    for (int i = 0; i < 4; i++) {
      int n = i * 32 + w * 8 + lr;
      async16(B + (size_t)(n0 + n) * KTOT + k0 + lc8, &Bs[(i * 32 + w * 8) * 64]);
    }
    __syncthreads();
#pragma unroll
    for (int kk = 0; kk < 2; kk++) {
      bf16x8 af[4], bfr[4];
#pragma unroll
      for (int mi = 0; mi < 4; mi++)
        af[mi] = *(const bf16x8*)&As[(wm * 64 + mi * 16 + mlane) * 64 + kk * 32 + q * 8];
#pragma unroll
      for (int ni = 0; ni < 4; ni++)
        bfr[ni] = *(const bf16x8*)&Bs[(wn * 64 + ni * 16 + mlane) * 64 + kk * 32 + q * 8];
#pragma unroll
      for (int mi = 0; mi < 4; mi++)
#pragma unroll
        for (int ni = 0; ni < 4; ni++)
          acc[mi][ni] = __builtin_amdgcn_mfma_f32_16x16x32_bf16(af[mi], bfr[ni], acc[mi][ni], 0, 0, 0);
    }
  }

#pragma unroll
  for (int mi = 0; mi < 4; mi++)
#pragma unroll
    for (int ni = 0; ni < 4; ni++) {
      int c = n0 + wn * 64 + ni * 16 + mlane;
#pragma unroll
      for (int rg = 0; rg < 4; rg++) {
        int r = row0 + wm * 64 + mi * 16 + q * 4 + rg;  // C/D: col=lane&15, row=(lane>>4)*4+reg
        if (r < M) {
          float v = acc[mi][ni][rg];
          if (SPLIT) {
            if (c < 256) ((unsigned short*)o1)[(size_t)r * 256 + c] = f2bf(v);
            else if (c < NLIM) ((unsigned short*)o2)[(size_t)r * 64 + (c - 256)] = f2bf(v);
          } else {
            ((float*)o1)[(size_t)r * 256 + c] = v;
          }
        }
      }
    }
}

// ---------------- propagation (gather-CSR, bf16 rows, fp32 accum) ----------------
// wave per node: lane reads bf16x4 (8B) -> 512B/wave row. out fp32 (feeds final matmul).
__global__ __launch_bounds__(256) void prop256(const unsigned short* __restrict__ H,
                                               const int* __restrict__ rp,
                                               const int* __restrict__ cs,
                                               const float* __restrict__ cw,
                                               const float* __restrict__ dinv,
                                               const float* __restrict__ bias,
                                               float* __restrict__ out, int n) {
  const int i = blockIdx.x * 4 + (threadIdx.x >> 6);
  const int l = threadIdx.x & 63;
  if (i >= n) return;
  const float di = dinv[i];
  float4 self = ld_bf4(H + (size_t)i * 256 + l * 4);
  float4 acc;
  acc.x = di * self.x; acc.y = di * self.y; acc.z = di * self.z; acc.w = di * self.w;
  const int e1 = rp[i + 1];
#pragma unroll 4
  for (int e = rp[i]; e < e1; e++) {
    float wgt = cw[e];
    float4 rrow = ld_bf4(H + (size_t)cs[e] * 256 + l * 4);
    acc.x += wgt * rrow.x; acc.y += wgt * rrow.y; acc.z += wgt * rrow.z; acc.w += wgt * rrow.w;
  }
  float4 b = *(const float4*)(bias + l * 4);
  float4 o;
  o.x = fmaxf(di * acc.x + b.x, 0.f);
  o.y = fmaxf(di * acc.y + b.y, 0.f);
  o.z = fmaxf(di * acc.z + b.z, 0.f);
  o.w = fmaxf(di * acc.w + b.w, 0.f);
  *(float4*)(out + (size_t)i * 256 + l * 4) = o;
}

// 64-dim: 16 lanes/node (bf16x4 each), 16 nodes/block. BIAS=1 adds bias (h2), else raw (q2).
template <int BIAS>
__global__ __launch_bounds__(256) void prop64(const unsigned short* __restrict__ H,
                                              const int* __restrict__ rp,
                                              const int* __restrict__ cs,
                                              const float* __restrict__ cw,
                                              const float* __restrict__ dinv,
                                              const float* __restrict__ bias,
                                              unsigned short* __restrict__ out, int n) {
  const int i = blockIdx.x * 16 + (threadIdx.x >> 4);
  const int l = threadIdx.x & 15;
  if (i >= n) return;
  const float di = dinv[i];
  float4 self = ld_bf4(H + (size_t)i * 64 + l * 4);
  float4 acc;
  acc.x = di * self.x; acc.y = di * self.y; acc.z = di * self.z; acc.w = di * self.w;
  const int e1 = rp[i + 1];
#pragma unroll 4
  for (int e = rp[i]; e < e1; e++) {
    float wgt = cw[e];
    float4 rrow = ld_bf4(H + (size_t)cs[e] * 64 + l * 4);
    acc.x += wgt * rrow.x; acc.y += wgt * rrow.y; acc.z += wgt * rrow.z; acc.w += wgt * rrow.w;
  }
  float4 o;
  o.x = di * acc.x; o.y = di * acc.y; o.z = di * acc.z; o.w = di * acc.w;
  if (BIAS) {
    float4 b = *(const float4*)(bias + l * 4);
    o.x += b.x; o.y += b.y; o.z += b.z; o.w += b.w;
  }
  ushort4 ob;
  ob.x = f2bf(o.x); ob.y = f2bf(o.y); ob.z = f2bf(o.z); ob.w = f2bf(o.w);
  *(ushort4*)(out + (size_t)i * 64 + l * 4) = ob;
}

// ---------------- fused tail: h = relu(h3+b21)+h1 ; out = h @ Wfc + bfc ----------------
__global__ __launch_bounds__(256) void final_k(const float* __restrict__ h1,
                                               const float* __restrict__ h3,
                                               const float* __restrict__ b21,
                                               const float* __restrict__ Wfc,
                                               const float* __restrict__ bfc,
                                               float* __restrict__ out, int M) {
  __shared__ float hs[16][260];
  __shared__ float wt[16][260];
  __shared__ float bs[16];
  const int t = threadIdx.x;
  for (int j = t; j < 4096; j += 256) { int k = j >> 4, c = j & 15; wt[c][k] = Wfc[j]; }
  if (t < 16) bs[t] = bfc[t];
  const float bb = b21[t];
  const int node0 = blockIdx.x * 16;
#pragma unroll
  for (int nl = 0; nl < 16; nl++) {
    int i = node0 + nl;
    float v = 0.f;
    if (i < M) {
      size_t o = (size_t)i * 256 + t;
      v = fmaxf(h3[o] + bb, 0.f) + h1[o];
    }
    hs[nl][t] = v;
  }
  __syncthreads();
  const int nl = t >> 4, c = t & 15;
  const int i = node0 + nl;
  if (i >= M) return;
  const float4* hp = (const float4*)&hs[nl][0];
  const float4* wp = (const float4*)&wt[c][0];
  float s = bs[c];
#pragma unroll 8
  for (int k4 = 0; k4 < 64; k4++) {
    float4 a = hp[k4], b = wp[k4];
    s += a.x * b.x + a.y * b.y + a.z * b.z + a.w * b.w;
  }
  out[(size_t)i * 16 + c] = s;
}

// ---------------- launch ----------------
extern "C" void kernel_launch(void* const* d_in, const int* in_sizes, int n_in,
                              void* d_out, int out_size, void* d_ws, size_t ws_size,
                              hipStream_t stream) {
  const float* X   = (const float*)d_in[0];
  const int*   ei1 = (const int*)d_in[1];
  const int*   ei2 = (const int*)d_in[2];
  const float* W10 = (const float*)d_in[3];
  const float* b10 = (const float*)d_in[4];
  const float* W20 = (const float*)d_in[5];
  const float* b20 = (const float*)d_in[6];
  const float* W21 = (const float*)d_in[7];
  const float* b21 = (const float*)d_in[8];
  const float* Wfc = (const float*)d_in[9];
  const float* bfc = (const float*)d_in[10];
  float* out = (float*)d_out;

  const int N = N_NODES;
  const int E1 = in_sizes[1] / 2, E2 = in_sizes[2] / 2;
  const int* src1 = ei1; const int* dst1 = ei1 + E1;
  const int* src2 = ei2; const int* dst2 = ei2 + E2;
  const int Emax = (E1 > E2) ? E1 : E2;

  char* p = (char*)d_ws;
  auto alloc = [&](size_t b) { char* r = p; p += (b + 255) & ~(size_t)255; return (void*)r; };
  int* cnts = (int*)alloc((size_t)2 * N * 4);  // cnt1,cnt2 adjacent (one memset)
  int *cnt1 = cnts, *cnt2 = cnts + N;
  int* cur1 = (int*)alloc((size_t)N * 4);
  int* cur2 = (int*)alloc((size_t)N * 4);
  int* rp1 = (int*)alloc((size_t)(N + 1) * 4);
  int* rp2 = (int*)alloc((size_t)(N + 1) * 4);
  float* dinv1 = (float*)alloc((size_t)N * 4);
  float* dinv2 = (float*)alloc((size_t)N * 4);
  int*   csr1s = (int*)alloc((size_t)E1 * 4);
  float* csr1w = (float*)alloc((size_t)E1 * 4);
  int*   csr2s = (int*)alloc((size_t)E2 * 4);
  float* csr2w = (float*)alloc((size_t)E2 * 4);
  unsigned short* WcatT = (unsigned short*)alloc(384 * 512 * 2);
  unsigned short* W21T  = (unsigned short*)alloc(256 * 64 * 2);
  unsigned short* Xb = (unsigned short*)alloc((size_t)N * 512 * 2);  // reused as h1 (N*256 f32)
  float* h1 = (float*)Xb;
  unsigned short* Xh1b = (unsigned short*)alloc((size_t)N * 256 * 2);  // bf16 GEMM1 out (256 cols)
  unsigned short* Xh2b = (unsigned short*)alloc((size_t)N * 64 * 2);   // bf16 GEMM1 out (64 cols)
  unsigned short* h2b  = (unsigned short*)alloc((size_t)N * 64 * 2);
  unsigned short* q2b  = (unsigned short*)alloc((size_t)N * 64 * 2);
  float* h3 = (float*)alloc((size_t)N * 256 * 4);

  hipMemsetAsync(cnts, 0, (size_t)2 * N * 4, stream);

  const int eblk = (Emax + 255) / 256;
  count_edges<<<dim3(eblk), 256, 0, stream>>>(dst1, dst2, cnt1, cnt2, E1, E2);
  scan_build2<<<dim3(2), 1024, 0, stream>>>(cnt1, rp1, cur1, dinv1, cnt2, rp2, cur2, dinv2, N);
  fill_csr<<<dim3(eblk), 256, 0, stream>>>(src1, dst1, cur1, dinv1, csr1s, csr1w, E1,
                                           src2, dst2, cur2, dinv2, csr2s, csr2w, E2);
  cvt_x<<<dim3(4096), 256, 0, stream>>>((const float4*)X, (ushort4*)Xb, N * FDIM / 4);
  cvt_w<<<dim3((384 * 512 + 256 * 64 + 255) / 256), 256, 0, stream>>>(W10, W20, W21, WcatT, W21T);
  // Xh1b = bf16(x@W10), Xh2b = bf16(x@W20)  (fused x @ [W10|W20], N padded to 384)
  gemm_bt<512, 1><<<dim3((N + 127) / 128, 3), 256, 0, stream>>>(Xb, WcatT, Xh1b, Xh2b, N, 320);
  // h1 = relu(prop1(Xh1) + b10)  fp32 (overwrites Xb)
  prop256<<<dim3((N + 3) / 4), 256, 0, stream>>>(Xh1b, rp1, csr1s, csr1w, dinv1, b10, h1, N);
  // h2 = prop2(Xh2) + b20  -> bf16
  prop64<1><<<dim3((N + 15) / 16), 256, 0, stream>>>(Xh2b, rp2, csr2s, csr2w, dinv2, b20, h2b, N);
  // q2 = prop2(h2) -> bf16
  prop64<0><<<dim3((N + 15) / 16), 256, 0, stream>>>(h2b, rp2, csr2s, csr2w, dinv2, nullptr, q2b, N);
  // h3 = q2 @ W21  fp32 (prop/transform commute)
  gemm_bt<64, 0><<<dim3((N + 127) / 128, 2), 256, 0, stream>>>(q2b, W21T, h3, nullptr, N, 256);
  // out = (relu(h3+b21)+h1) @ Wfc + bfc
  final_k<<<dim3((N + 15) / 16), 256, 0, stream>>>(h1, h3, b21, Wfc, bfc, out, N);
}

// Round 4
// 574.030 us; speedup vs baseline: 1.4799x; 1.1765x over previous
//
#include <hip/hip_runtime.h>
#include <hip/hip_bf16.h>
#include <cstdint>
#include <cstddef>

#define N_NODES 50000
#define FDIM 512
#define NCHUNK 49  // ceil(50000/1024)

typedef __bf16 bf16_t;
typedef bf16_t bf16x8 __attribute__((ext_vector_type(8)));
typedef float f32x4 __attribute__((ext_vector_type(4)));

__device__ __forceinline__ unsigned short f2bf(float f) {
  union { float f; uint32_t u; } c; c.f = f;
  uint32_t u = c.u;
  uint32_t r = (u + 0x7fffu + ((u >> 16) & 1u)) >> 16;  // RNE
  return (unsigned short)r;
}
__device__ __forceinline__ float bf2f(unsigned short u) {
  union { uint32_t i; float f; } c; c.i = (uint32_t)u << 16; return c.f;
}
__device__ __forceinline__ float4 ld_bf4(const unsigned short* p) {
  ushort4 u = *(const ushort4*)p;
  float4 r; r.x = bf2f(u.x); r.y = bf2f(u.y); r.z = bf2f(u.z); r.w = bf2f(u.w);
  return r;
}
__device__ __forceinline__ void async16(const void* g, void* l) {
  __builtin_amdgcn_global_load_lds((const __attribute__((address_space(1))) void*)g,
                                   (__attribute__((address_space(3))) void*)l, 16, 0, 0);
}

// ---------------- CSR build ----------------
__global__ void count_edges(const int* __restrict__ d1, const int* __restrict__ d2,
                            int* __restrict__ c1, int* __restrict__ c2, int E1, int E2) {
  int e = blockIdx.x * 256 + threadIdx.x;
  if (e < E1) atomicAdd(&c1[d1[e]], 1);
  if (e < E2) atomicAdd(&c2[d2[e]], 1);
}

// Pass 1: per-1024-chunk sums. grid (NCHUNK, 2).
__global__ __launch_bounds__(256) void chunk_sum(const int* __restrict__ cnt1,
                                                 const int* __restrict__ cnt2,
                                                 int* __restrict__ csum, int n) {
  const int g = blockIdx.y;
  const int* cnt = g ? cnt2 : cnt1;
  const int base = blockIdx.x * 1024 + threadIdx.x * 4;
  int s = 0;
  if (base < n) {  // n % 4 == 0 so full int4 is safe
    int4 v = *(const int4*)(cnt + base);
    s = v.x + v.y + v.z + v.w;
  }
  for (int off = 32; off; off >>= 1) s += __shfl_down(s, off);
  __shared__ int ws[4];
  if ((threadIdx.x & 63) == 0) ws[threadIdx.x >> 6] = s;
  __syncthreads();
  if (threadIdx.x == 0) csum[g * NCHUNK + blockIdx.x] = ws[0] + ws[1] + ws[2] + ws[3];
}

// Pass 2: one block; wave g shuffle-scans its NCHUNK sums -> exclusive offsets in-place.
__global__ __launch_bounds__(128) void scan_chunks(int* __restrict__ csum) {
  const int g = threadIdx.x >> 6, l = threadIdx.x & 63;
  int orig = (l < NCHUNK) ? csum[g * NCHUNK + l] : 0;
  int v = orig;
  for (int off = 1; off < 64; off <<= 1) {
    int u = __shfl_up(v, off);
    if (l >= off) v += u;
  }
  if (l < NCHUNK) csum[g * NCHUNK + l] = v - orig;  // exclusive
}

// Pass 3: per-chunk LDS scan + chunk offset -> rowptr, cur, dinv. grid (NCHUNK, 2).
__global__ __launch_bounds__(256) void scan_final(const int* __restrict__ cnt1,
                                                  const int* __restrict__ cnt2,
                                                  const int* __restrict__ csum,
                                                  int* __restrict__ rp1, int* __restrict__ cur1,
                                                  float* __restrict__ dv1,
                                                  int* __restrict__ rp2, int* __restrict__ cur2,
                                                  float* __restrict__ dv2, int n) {
  const int g = blockIdx.y;
  const int* cnt = g ? cnt2 : cnt1;
  int* rowptr = g ? rp2 : rp1;
  int* cur = g ? cur2 : cur1;
  float* dinv = g ? dv2 : dv1;
  const int t = threadIdx.x;
  const int base = blockIdx.x * 1024 + t * 4;
  int4 c = {0, 0, 0, 0};
  if (base < n) c = *(const int4*)(cnt + base);
  const int tsum = c.x + c.y + c.z + c.w;
  __shared__ int ts[256];
  ts[t] = tsum;
  __syncthreads();
  for (int off = 1; off < 256; off <<= 1) {
    int u = (t >= off) ? ts[t - off] : 0;
    __syncthreads();
    ts[t] += u;
    __syncthreads();
  }
  int pre = csum[g * NCHUNK + blockIdx.x] + ts[t] - tsum;  // exclusive within graph
  if (base < n) {
    int4 p; p.x = pre; p.y = pre + c.x; p.z = p.y + c.y; p.w = p.z + c.z;
    *(int4*)(rowptr + base) = p;
    *(int4*)(cur + base) = p;
    float4 dv;
    dv.x = rsqrtf((float)c.x + 1.0f); dv.y = rsqrtf((float)c.y + 1.0f);
    dv.z = rsqrtf((float)c.z + 1.0f); dv.w = rsqrtf((float)c.w + 1.0f);
    *(float4*)(dinv + base) = dv;
    if (base + 3 == n - 1) rowptr[n] = p.w + c.w;
  }
}

__global__ void fill_csr(const int* __restrict__ s1, const int* __restrict__ d1,
                         int* __restrict__ cur1, int* __restrict__ c1s, int E1,
                         const int* __restrict__ s2, const int* __restrict__ d2,
                         int* __restrict__ cur2, int* __restrict__ c2s, int E2) {
  int e = blockIdx.x * 256 + threadIdx.x;
  if (e < E1) {
    int pos = atomicAdd(&cur1[d1[e]], 1);
    c1s[pos] = s1[e];
  }
  if (e < E2) {
    int pos = atomicAdd(&cur2[d2[e]], 1);
    c2s[pos] = s2[e];
  }
}

// ---------------- dtype converts ----------------
__global__ void cvt_x(const float4* __restrict__ X, ushort4* __restrict__ out, int n4) {
  int stride = gridDim.x * 256;
  for (int i = blockIdx.x * 256 + threadIdx.x; i < n4; i += stride) {
    float4 v = X[i];
    ushort4 o;
    o.x = f2bf(v.x); o.y = f2bf(v.y); o.z = f2bf(v.z); o.w = f2bf(v.w);
    out[i] = o;
  }
}

// WcatT[384][512]: n<256 -> W10 col n; 256<=n<320 -> W20 col n-256; else 0 (pad)
// W21T[256][64]: W21 transposed
__global__ void cvt_w(const float* __restrict__ W10, const float* __restrict__ W20,
                      const float* __restrict__ W21, unsigned short* __restrict__ WcatT,
                      unsigned short* __restrict__ W21T) {
  int j = blockIdx.x * 256 + threadIdx.x;
  const int T1 = 384 * 512;
  if (j < T1) {
    int n = j >> 9, k = j & 511;
    float v = (n < 256) ? W10[k * 256 + n] : ((n < 320) ? W20[k * 64 + (n - 256)] : 0.f);
    WcatT[j] = f2bf(v);
  } else {
    int j2 = j - T1;
    if (j2 < 256 * 64) {
      int n = j2 >> 6, k = j2 & 63;
      W21T[j2] = f2bf(W21[k * 256 + n]);
    }
  }
}

// ---------------- bf16 MFMA GEMM: C[M,N] = A[M,KTOT] * B^T[N,KTOT] ----------------
// m97 structure: tile 128(M) x 128(N), BK=64, 256 threads (4 waves), wave = 64x64, 4x4 acc.
// SPLIT=1: bf16 dual-output (c<256 -> o1 stride 256; 256<=c<NLIM -> o2 stride 64)
// SPLIT=0: f32 single output (stride 256)
template <int KTOT, int SPLIT>
__global__ __launch_bounds__(256) void gemm_bt(const unsigned short* __restrict__ A,
                                               const unsigned short* __restrict__ B,
                                               void* __restrict__ o1, void* __restrict__ o2,
                                               int M, int NLIM) {
  __shared__ unsigned short As[128 * 64];
  __shared__ unsigned short Bs[128 * 64];
  const int tid = threadIdx.x;
  const int w = tid >> 6, lane = tid & 63;
  const int row0 = blockIdx.x * 128;
  const int n0 = blockIdx.y * 128;
  const int wm = w >> 1, wn = w & 1;          // wave 2x2 grid, each 64(M)x64(N)
  const int lr = lane >> 3, lc8 = (lane & 7) * 8;
  const int mlane = lane & 15, q = lane >> 4;

  f32x4 acc[4][4];
#pragma unroll
  for (int mi = 0; mi < 4; mi++)
#pragma unroll
    for (int ni = 0; ni < 4; ni++) {
      f32x4 z = {0.f, 0.f, 0.f, 0.f};
      acc[mi][ni] = z;
    }

  for (int k0 = 0; k0 < KTOT; k0 += 64) {
    __syncthreads();
#pragma unroll
    for (int i = 0; i < 4; i++) {
      int gr = row0 + i * 32 + w * 8 + lr;
      if (gr > M - 1) gr = M - 1;  // clamp; stores masked in epilogue
      async16(A + (size_t)gr * KTOT + k0 + lc8, &As[(i * 32 + w * 8) * 64]);
    }
#pragma unroll
    for (int i = 0; i < 4; i++) {
      int n = i * 32 + w * 8 + lr;
      async16(B + (size_t)(n0 + n) * KTOT + k0 + lc8, &Bs[(i * 32 + w * 8) * 64]);
    }
    __syncthreads();
#pragma unroll
    for (int kk = 0; kk < 2; kk++) {
      bf16x8 af[4], bfr[4];
#pragma unroll
      for (int mi = 0; mi < 4; mi++)
        af[mi] = *(const bf16x8*)&As[(wm * 64 + mi * 16 + mlane) * 64 + kk * 32 + q * 8];
#pragma unroll
      for (int ni = 0; ni < 4; ni++)
        bfr[ni] = *(const bf16x8*)&Bs[(wn * 64 + ni * 16 + mlane) * 64 + kk * 32 + q * 8];
#pragma unroll
      for (int mi = 0; mi < 4; mi++)
#pragma unroll
        for (int ni = 0; ni < 4; ni++)
          acc[mi][ni] = __builtin_amdgcn_mfma_f32_16x16x32_bf16(af[mi], bfr[ni], acc[mi][ni], 0, 0, 0);
    }
  }

#pragma unroll
  for (int mi = 0; mi < 4; mi++)
#pragma unroll
    for (int ni = 0; ni < 4; ni++) {
      int c = n0 + wn * 64 + ni * 16 + mlane;
#pragma unroll
      for (int rg = 0; rg < 4; rg++) {
        int r = row0 + wm * 64 + mi * 16 + q * 4 + rg;  // C/D: col=lane&15, row=(lane>>4)*4+reg
        if (r < M) {
          float v = acc[mi][ni][rg];
          if (SPLIT) {
            if (c < 256) ((unsigned short*)o1)[(size_t)r * 256 + c] = f2bf(v);
            else if (c < NLIM) ((unsigned short*)o2)[(size_t)r * 64 + (c - 256)] = f2bf(v);
          } else {
            ((float*)o1)[(size_t)r * 256 + c] = v;
          }
        }
      }
    }
}

// ---------------- propagation (gather-CSR, bf16 rows, fp32 accum) ----------------
// wave per node: lane reads bf16x4 (8B) -> 512B/wave row. weight = dinv[src] (broadcast).
__global__ __launch_bounds__(256) void prop256(const unsigned short* __restrict__ H,
                                               const int* __restrict__ rp,
                                               const int* __restrict__ cs,
                                               const float* __restrict__ dinv,
                                               const float* __restrict__ bias,
                                               float* __restrict__ out, int n) {
  const int i = blockIdx.x * 4 + (threadIdx.x >> 6);
  const int l = threadIdx.x & 63;
  if (i >= n) return;
  const float di = dinv[i];
  float4 self = ld_bf4(H + (size_t)i * 256 + l * 4);
  float4 acc;
  acc.x = di * self.x; acc.y = di * self.y; acc.z = di * self.z; acc.w = di * self.w;
  const int e1 = rp[i + 1];
#pragma unroll 4
  for (int e = rp[i]; e < e1; e++) {
    int s = cs[e];
    float wgt = dinv[s];
    float4 rrow = ld_bf4(H + (size_t)s * 256 + l * 4);
    acc.x += wgt * rrow.x; acc.y += wgt * rrow.y; acc.z += wgt * rrow.z; acc.w += wgt * rrow.w;
  }
  float4 b = *(const float4*)(bias + l * 4);
  float4 o;
  o.x = fmaxf(di * acc.x + b.x, 0.f);
  o.y = fmaxf(di * acc.y + b.y, 0.f);
  o.z = fmaxf(di * acc.z + b.z, 0.f);
  o.w = fmaxf(di * acc.w + b.w, 0.f);
  *(float4*)(out + (size_t)i * 256 + l * 4) = o;
}

// 64-dim: 16 lanes/node (bf16x4 each), 16 nodes/block. BIAS=1 adds bias (h2), else raw (q2).
template <int BIAS>
__global__ __launch_bounds__(256) void prop64(const unsigned short* __restrict__ H,
                                              const int* __restrict__ rp,
                                              const int* __restrict__ cs,
                                              const float* __restrict__ dinv,
                                              const float* __restrict__ bias,
                                              unsigned short* __restrict__ out, int n) {
  const int i = blockIdx.x * 16 + (threadIdx.x >> 4);
  const int l = threadIdx.x & 15;
  if (i >= n) return;
  const float di = dinv[i];
  float4 self = ld_bf4(H + (size_t)i * 64 + l * 4);
  float4 acc;
  acc.x = di * self.x; acc.y = di * self.y; acc.z = di * self.z; acc.w = di * self.w;
  const int e1 = rp[i + 1];
#pragma unroll 4
  for (int e = rp[i]; e < e1; e++) {
    int s = cs[e];
    float wgt = dinv[s];
    float4 rrow = ld_bf4(H + (size_t)s * 64 + l * 4);
    acc.x += wgt * rrow.x; acc.y += wgt * rrow.y; acc.z += wgt * rrow.z; acc.w += wgt * rrow.w;
  }
  float4 o;
  o.x = di * acc.x; o.y = di * acc.y; o.z = di * acc.z; o.w = di * acc.w;
  if (BIAS) {
    float4 b = *(const float4*)(bias + l * 4);
    o.x += b.x; o.y += b.y; o.z += b.z; o.w += b.w;
  }
  ushort4 ob;
  ob.x = f2bf(o.x); ob.y = f2bf(o.y); ob.z = f2bf(o.z); ob.w = f2bf(o.w);
  *(ushort4*)(out + (size_t)i * 64 + l * 4) = ob;
}

// ---------------- fused tail: h = relu(h3+b21)+h1 ; out = h @ Wfc + bfc ----------------
__global__ __launch_bounds__(256) void final_k(const float* __restrict__ h1,
                                               const float* __restrict__ h3,
                                               const float* __restrict__ b21,
                                               const float* __restrict__ Wfc,
                                               const float* __restrict__ bfc,
                                               float* __restrict__ out, int M) {
  __shared__ float hs[16][260];
  __shared__ float wt[16][260];
  __shared__ float bs[16];
  const int t = threadIdx.x;
  for (int j = t; j < 4096; j += 256) { int k = j >> 4, c = j & 15; wt[c][k] = Wfc[j]; }
  if (t < 16) bs[t] = bfc[t];
  const float bb = b21[t];
  const int node0 = blockIdx.x * 16;
#pragma unroll
  for (int nl = 0; nl < 16; nl++) {
    int i = node0 + nl;
    float v = 0.f;
    if (i < M) {
      size_t o = (size_t)i * 256 + t;
      v = fmaxf(h3[o] + bb, 0.f) + h1[o];
    }
    hs[nl][t] = v;
  }
  __syncthreads();
  const int nl = t >> 4, c = t & 15;
  const int i = node0 + nl;
  if (i >= M) return;
  const float4* hp = (const float4*)&hs[nl][0];
  const float4* wp = (const float4*)&wt[c][0];
  float s = bs[c];
#pragma unroll 8
  for (int k4 = 0; k4 < 64; k4++) {
    float4 a = hp[k4], b = wp[k4];
    s += a.x * b.x + a.y * b.y + a.z * b.z + a.w * b.w;
  }
  out[(size_t)i * 16 + c] = s;
}

// ---------------- launch ----------------
extern "C" void kernel_launch(void* const* d_in, const int* in_sizes, int n_in,
                              void* d_out, int out_size, void* d_ws, size_t ws_size,
                              hipStream_t stream) {
  const float* X   = (const float*)d_in[0];
  const int*   ei1 = (const int*)d_in[1];
  const int*   ei2 = (const int*)d_in[2];
  const float* W10 = (const float*)d_in[3];
  const float* b10 = (const float*)d_in[4];
  const float* W20 = (const float*)d_in[5];
  const float* b20 = (const float*)d_in[6];
  const float* W21 = (const float*)d_in[7];
  const float* b21 = (const float*)d_in[8];
  const float* Wfc = (const float*)d_in[9];
  const float* bfc = (const float*)d_in[10];
  float* out = (float*)d_out;

  const int N = N_NODES;
  const int E1 = in_sizes[1] / 2, E2 = in_sizes[2] / 2;
  const int* src1 = ei1; const int* dst1 = ei1 + E1;
  const int* src2 = ei2; const int* dst2 = ei2 + E2;
  const int Emax = (E1 > E2) ? E1 : E2;

  char* p = (char*)d_ws;
  auto alloc = [&](size_t b) { char* r = p; p += (b + 255) & ~(size_t)255; return (void*)r; };
  int* cnts = (int*)alloc((size_t)2 * N * 4);  // cnt1,cnt2 adjacent (one memset)
  int *cnt1 = cnts, *cnt2 = cnts + N;
  int* cur1 = (int*)alloc((size_t)N * 4);
  int* cur2 = (int*)alloc((size_t)N * 4);
  int* rp1 = (int*)alloc((size_t)(N + 1) * 4);
  int* rp2 = (int*)alloc((size_t)(N + 1) * 4);
  float* dinv1 = (float*)alloc((size_t)N * 4);
  float* dinv2 = (float*)alloc((size_t)N * 4);
  int* csum = (int*)alloc((size_t)2 * NCHUNK * 4);
  int* csr1s = (int*)alloc((size_t)E1 * 4);
  int* csr2s = (int*)alloc((size_t)E2 * 4);
  unsigned short* WcatT = (unsigned short*)alloc(384 * 512 * 2);
  unsigned short* W21T  = (unsigned short*)alloc(256 * 64 * 2);
  unsigned short* Xb = (unsigned short*)alloc((size_t)N * 512 * 2);  // reused as h1 (N*256 f32)
  float* h1 = (float*)Xb;
  unsigned short* Xh1b = (unsigned short*)alloc((size_t)N * 256 * 2);  // bf16 GEMM1 out (256 cols)
  unsigned short* Xh2b = (unsigned short*)alloc((size_t)N * 64 * 2);   // bf16 GEMM1 out (64 cols)
  unsigned short* h2b  = (unsigned short*)alloc((size_t)N * 64 * 2);
  unsigned short* q2b  = (unsigned short*)alloc((size_t)N * 64 * 2);
  float* h3 = (float*)alloc((size_t)N * 256 * 4);

  hipMemsetAsync(cnts, 0, (size_t)2 * N * 4, stream);

  const int eblk = (Emax + 255) / 256;
  count_edges<<<dim3(eblk), 256, 0, stream>>>(dst1, dst2, cnt1, cnt2, E1, E2);
  chunk_sum<<<dim3(NCHUNK, 2), 256, 0, stream>>>(cnt1, cnt2, csum, N);
  scan_chunks<<<dim3(1), 128, 0, stream>>>(csum);
  scan_final<<<dim3(NCHUNK, 2), 256, 0, stream>>>(cnt1, cnt2, csum, rp1, cur1, dinv1,
                                                  rp2, cur2, dinv2, N);
  fill_csr<<<dim3(eblk), 256, 0, stream>>>(src1, dst1, cur1, csr1s, E1,
                                           src2, dst2, cur2, csr2s, E2);
  cvt_x<<<dim3(4096), 256, 0, stream>>>((const float4*)X, (ushort4*)Xb, N * FDIM / 4);
  cvt_w<<<dim3((384 * 512 + 256 * 64 + 255) / 256), 256, 0, stream>>>(W10, W20, W21, WcatT, W21T);
  // Xh1b = bf16(x@W10), Xh2b = bf16(x@W20)  (fused x @ [W10|W20], N padded to 384)
  gemm_bt<512, 1><<<dim3((N + 127) / 128, 3), 256, 0, stream>>>(Xb, WcatT, Xh1b, Xh2b, N, 320);
  // h1 = relu(prop1(Xh1) + b10)  fp32 (overwrites Xb)
  prop256<<<dim3((N + 3) / 4), 256, 0, stream>>>(Xh1b, rp1, csr1s, dinv1, b10, h1, N);
  // h2 = prop2(Xh2) + b20  -> bf16
  prop64<1><<<dim3((N + 15) / 16), 256, 0, stream>>>(Xh2b, rp2, csr2s, dinv2, b20, h2b, N);
  // q2 = prop2(h2) -> bf16
  prop64<0><<<dim3((N + 15) / 16), 256, 0, stream>>>(h2b, rp2, csr2s, dinv2, nullptr, q2b, N);
  // h3 = q2 @ W21  fp32 (prop/transform commute)
  gemm_bt<64, 0><<<dim3((N + 127) / 128, 2), 256, 0, stream>>>(q2b, W21T, h3, nullptr, N, 256);
  // out = (relu(h3+b21)+h1) @ Wfc + bfc
  final_k<<<dim3((N + 15) / 16), 256, 0, stream>>>(h1, h3, b21, Wfc, bfc, out, N);
}

// Round 5
// 473.069 us; speedup vs baseline: 1.7957x; 1.2134x over previous
//
#include <hip/hip_runtime.h>
#include <hip/hip_bf16.h>
#include <cstdint>
#include <cstddef>

#define N_NODES 50000
#define FDIM 512
#define NBKT 391        // ceil(50000/128) buckets of 128 dst nodes
#define CHUNK 8192      // edges per binning block
#define BCAP 4096       // max edges per bucket (Poisson(2046), sigma 45 -> cap is 45 sigma)

typedef __bf16 bf16_t;
typedef bf16_t bf16x8 __attribute__((ext_vector_type(8)));
typedef float f32x4 __attribute__((ext_vector_type(4)));

__device__ __forceinline__ unsigned short f2bf(float f) {
  union { float f; uint32_t u; } c; c.f = f;
  uint32_t u = c.u;
  uint32_t r = (u + 0x7fffu + ((u >> 16) & 1u)) >> 16;  // RNE
  return (unsigned short)r;
}
__device__ __forceinline__ float bf2f(unsigned short u) {
  union { uint32_t i; float f; } c; c.i = (uint32_t)u << 16; return c.f;
}
__device__ __forceinline__ float4 ld_bf4(const unsigned short* p) {
  ushort4 u = *(const ushort4*)p;
  float4 r; r.x = bf2f(u.x); r.y = bf2f(u.y); r.z = bf2f(u.z); r.w = bf2f(u.w);
  return r;
}
__device__ __forceinline__ void async16(const void* g, void* l) {
  __builtin_amdgcn_global_load_lds((const __attribute__((address_space(1))) void*)g,
                                   (__attribute__((address_space(3))) void*)l, 16, 0, 0);
}

// ---------------- CSR build: LDS-binned bucket sort, no global atomics ----------------
// Phase A: per-chunk histogram over NBKT buckets -> M[chunk][bkt]
__global__ __launch_bounds__(256) void binA(const int* __restrict__ d1, const int* __restrict__ d2,
                                            int* __restrict__ M1, int* __restrict__ M2,
                                            int E1, int E2, int nch1, int nch2) {
  const int g = blockIdx.y;
  const int* dst = g ? d2 : d1;
  int* M = g ? M2 : M1;
  const int E = g ? E2 : E1;
  const int nch = g ? nch2 : nch1;
  const int chunk = blockIdx.x;
  if (chunk >= nch) return;
  __shared__ int cnt[NBKT];
  for (int j = threadIdx.x; j < NBKT; j += 256) cnt[j] = 0;
  __syncthreads();
  const int base = chunk * CHUNK;
#pragma unroll 4
  for (int i = 0; i < CHUNK / 256; i++) {
    int e = base + i * 256 + threadIdx.x;
    if (e < E) atomicAdd(&cnt[dst[e] >> 7], 1);
  }
  __syncthreads();
  for (int j = threadIdx.x; j < NBKT; j += 256) M[chunk * NBKT + j] = cnt[j];
}

// Phase A2: per graph, convert M in place to global start offsets; bases[g][bkt] = bucket start.
__global__ __launch_bounds__(512) void bin_offsets(int* __restrict__ M1, int* __restrict__ M2,
                                                   int* __restrict__ bases,
                                                   int nch1, int nch2, int E1, int E2) {
  const int g = blockIdx.x;
  int* M = g ? M2 : M1;
  const int nch = g ? nch2 : nch1;
  int* base = bases + g * (NBKT + 1);
  const int E = g ? E2 : E1;
  const int t = threadIdx.x;
  __shared__ int tot[512];
  int running = 0;
  if (t < NBKT) {
    for (int b = 0; b < nch; b++) {
      int v = M[b * NBKT + t];
      M[b * NBKT + t] = running;
      running += v;
    }
  }
  tot[t] = (t < NBKT) ? running : 0;
  __syncthreads();
  for (int off = 1; off < 512; off <<= 1) {
    int u = (t >= off) ? tot[t - off] : 0;
    __syncthreads();
    tot[t] += u;
    __syncthreads();
  }
  int ex = (t == 0) ? 0 : tot[t - 1];
  if (t < NBKT) {
    base[t] = ex;
    for (int b = 0; b < nch; b++) M[b * NBKT + t] += ex;
  }
  if (t == NBKT) base[NBKT] = E;
}

// Phase B: scatter packed (dst<<16|src) into bucket-grouped ebuf (run-coalesced writes).
__global__ __launch_bounds__(256) void binB(const int* __restrict__ s1, const int* __restrict__ d1,
                                            const int* __restrict__ M1, unsigned* __restrict__ eb1,
                                            int E1, int nch1,
                                            const int* __restrict__ s2, const int* __restrict__ d2,
                                            const int* __restrict__ M2, unsigned* __restrict__ eb2,
                                            int E2, int nch2) {
  const int g = blockIdx.y;
  const int* src = g ? s2 : s1;
  const int* dst = g ? d2 : d1;
  const int* M = g ? M2 : M1;
  unsigned* eb = g ? eb2 : eb1;
  const int E = g ? E2 : E1;
  const int nch = g ? nch2 : nch1;
  const int chunk = blockIdx.x;
  if (chunk >= nch) return;
  __shared__ int gbase[NBKT];
  __shared__ int cur[NBKT];
  for (int j = threadIdx.x; j < NBKT; j += 256) {
    gbase[j] = M[chunk * NBKT + j];
    cur[j] = 0;
  }
  __syncthreads();
  const int base = chunk * CHUNK;
#pragma unroll 4
  for (int i = 0; i < CHUNK / 256; i++) {
    int e = base + i * 256 + threadIdx.x;
    if (e < E) {
      int d = dst[e];
      int b = d >> 7;
      int pos = gbase[b] + atomicAdd(&cur[b], 1);
      eb[pos] = ((unsigned)d << 16) | (unsigned)src[e];
    }
  }
}

// Phase C: per-bucket LDS counting sort -> csr src list (coalesced), rowptr, dinv.
__global__ __launch_bounds__(256) void binC(const unsigned* __restrict__ eb1,
                                            const unsigned* __restrict__ eb2,
                                            const int* __restrict__ bases,
                                            int* __restrict__ rp1, float* __restrict__ dv1,
                                            int* __restrict__ cs1,
                                            int* __restrict__ rp2, float* __restrict__ dv2,
                                            int* __restrict__ cs2, int n) {
  const int g = blockIdx.y;
  const unsigned* eb = g ? eb2 : eb1;
  const int* base = bases + g * (NBKT + 1);
  int* rp = g ? rp2 : rp1;
  float* dv = g ? dv2 : dv1;
  int* cs = g ? cs2 : cs1;
  const int bkt = blockIdx.x;
  const int e0 = base[bkt], e1 = base[bkt + 1];
  const int cnt = e1 - e0;
  const int node0 = bkt << 7;
  const int t = threadIdx.x;
  __shared__ unsigned stage[BCAP];
  __shared__ int sorted[BCAP];
  __shared__ int dcnt[128], dcur[128], dscan[128];
  if (t < 128) dcnt[t] = 0;
  __syncthreads();
  for (int i = t; i < cnt; i += 256) {
    unsigned pe = eb[e0 + i];
    stage[i] = pe;
    atomicAdd(&dcnt[(pe >> 16) & 127], 1);
  }
  __syncthreads();
  if (t < 128) dscan[t] = dcnt[t];
  __syncthreads();
  for (int off = 1; off < 128; off <<= 1) {
    int u = (t < 128 && t >= off) ? dscan[t - off] : 0;
    __syncthreads();
    if (t < 128) dscan[t] += u;
    __syncthreads();
  }
  if (t < 128) {
    int ex = dscan[t] - dcnt[t];  // exclusive within bucket
    dcur[t] = ex;
    int node = node0 + t;
    if (node < n) {
      rp[node] = e0 + ex;
      dv[node] = rsqrtf((float)dcnt[t] + 1.0f);  // deg includes self-loop
    }
  }
  __syncthreads();
  for (int i = t; i < cnt; i += 256) {
    unsigned pe = stage[i];
    int d = (pe >> 16) & 127;
    int pos = atomicAdd(&dcur[d], 1);
    sorted[pos] = (int)(pe & 0xFFFFu);
  }
  __syncthreads();
  for (int i = t; i < cnt; i += 256) cs[e0 + i] = sorted[i];
  if (bkt == NBKT - 1 && t == 0) rp[n] = base[NBKT];
}

// ---------------- dtype converts ----------------
__global__ void cvt_x(const float4* __restrict__ X, ushort4* __restrict__ out, int n4) {
  int stride = gridDim.x * 256;
  for (int i = blockIdx.x * 256 + threadIdx.x; i < n4; i += stride) {
    float4 v = X[i];
    ushort4 o;
    o.x = f2bf(v.x); o.y = f2bf(v.y); o.z = f2bf(v.z); o.w = f2bf(v.w);
    out[i] = o;
  }
}

// WcatT[384][512]: n<256 -> W10 col n; 256<=n<320 -> W20 col n-256; else 0 (pad)
// W21T[256][64]: W21 transposed
__global__ void cvt_w(const float* __restrict__ W10, const float* __restrict__ W20,
                      const float* __restrict__ W21, unsigned short* __restrict__ WcatT,
                      unsigned short* __restrict__ W21T) {
  int j = blockIdx.x * 256 + threadIdx.x;
  const int T1 = 384 * 512;
  if (j < T1) {
    int n = j >> 9, k = j & 511;
    float v = (n < 256) ? W10[k * 256 + n] : ((n < 320) ? W20[k * 64 + (n - 256)] : 0.f);
    WcatT[j] = f2bf(v);
  } else {
    int j2 = j - T1;
    if (j2 < 256 * 64) {
      int n = j2 >> 6, k = j2 & 63;
      W21T[j2] = f2bf(W21[k * 256 + n]);
    }
  }
}

// ---------------- bf16 MFMA GEMM: C[M,N] = A[M,KTOT] * B^T[N,KTOT] ----------------
// m97 structure: tile 128(M) x 128(N), BK=64, 256 threads (4 waves), wave = 64x64, 4x4 acc.
// SPLIT=1: bf16 dual-output (c<256 -> o1 stride 256; 256<=c<NLIM -> o2 stride 64)
// SPLIT=0: f32 single output (stride 256)
template <int KTOT, int SPLIT>
__global__ __launch_bounds__(256) void gemm_bt(const unsigned short* __restrict__ A,
                                               const unsigned short* __restrict__ B,
                                               void* __restrict__ o1, void* __restrict__ o2,
                                               int M, int NLIM) {
  __shared__ unsigned short As[128 * 64];
  __shared__ unsigned short Bs[128 * 64];
  const int tid = threadIdx.x;
  const int w = tid >> 6, lane = tid & 63;
  const int row0 = blockIdx.x * 128;
  const int n0 = blockIdx.y * 128;
  const int wm = w >> 1, wn = w & 1;          // wave 2x2 grid, each 64(M)x64(N)
  const int lr = lane >> 3, lc8 = (lane & 7) * 8;
  const int mlane = lane & 15, q = lane >> 4;

  f32x4 acc[4][4];
#pragma unroll
  for (int mi = 0; mi < 4; mi++)
#pragma unroll
    for (int ni = 0; ni < 4; ni++) {
      f32x4 z = {0.f, 0.f, 0.f, 0.f};
      acc[mi][ni] = z;
    }

  for (int k0 = 0; k0 < KTOT; k0 += 64) {
    __syncthreads();
#pragma unroll
    for (int i = 0; i < 4; i++) {
      int gr = row0 + i * 32 + w * 8 + lr;
      if (gr > M - 1) gr = M - 1;  // clamp; stores masked in epilogue
      async16(A + (size_t)gr * KTOT + k0 + lc8, &As[(i * 32 + w * 8) * 64]);
    }
#pragma unroll
    for (int i = 0; i < 4; i++) {
      int n = i * 32 + w * 8 + lr;
      async16(B + (size_t)(n0 + n) * KTOT + k0 + lc8, &Bs[(i * 32 + w * 8) * 64]);
    }
    __syncthreads();
#pragma unroll
    for (int kk = 0; kk < 2; kk++) {
      bf16x8 af[4], bfr[4];
#pragma unroll
      for (int mi = 0; mi < 4; mi++)
        af[mi] = *(const bf16x8*)&As[(wm * 64 + mi * 16 + mlane) * 64 + kk * 32 + q * 8];
#pragma unroll
      for (int ni = 0; ni < 4; ni++)
        bfr[ni] = *(const bf16x8*)&Bs[(wn * 64 + ni * 16 + mlane) * 64 + kk * 32 + q * 8];
#pragma unroll
      for (int mi = 0; mi < 4; mi++)
#pragma unroll
        for (int ni = 0; ni < 4; ni++)
          acc[mi][ni] = __builtin_amdgcn_mfma_f32_16x16x32_bf16(af[mi], bfr[ni], acc[mi][ni], 0, 0, 0);
    }
  }

#pragma unroll
  for (int mi = 0; mi < 4; mi++)
#pragma unroll
    for (int ni = 0; ni < 4; ni++) {
      int c = n0 + wn * 64 + ni * 16 + mlane;
#pragma unroll
      for (int rg = 0; rg < 4; rg++) {
        int r = row0 + wm * 64 + mi * 16 + q * 4 + rg;  // C/D: col=lane&15, row=(lane>>4)*4+reg
        if (r < M) {
          float v = acc[mi][ni][rg];
          if (SPLIT) {
            if (c < 256) ((unsigned short*)o1)[(size_t)r * 256 + c] = f2bf(v);
            else if (c < NLIM) ((unsigned short*)o2)[(size_t)r * 64 + (c - 256)] = f2bf(v);
          } else {
            ((float*)o1)[(size_t)r * 256 + c] = v;
          }
        }
      }
    }
}

// ---------------- propagation (gather-CSR, bf16 rows, fp32 accum) ----------------
// wave per node: lane reads bf16x4 (8B) -> 512B/wave row. weight = dinv[src] (broadcast).
__global__ __launch_bounds__(256) void prop256(const unsigned short* __restrict__ H,
                                               const int* __restrict__ rp,
                                               const int* __restrict__ cs,
                                               const float* __restrict__ dinv,
                                               const float* __restrict__ bias,
                                               float* __restrict__ out, int n) {
  const int i = blockIdx.x * 4 + (threadIdx.x >> 6);
  const int l = threadIdx.x & 63;
  if (i >= n) return;
  const float di = dinv[i];
  float4 self = ld_bf4(H + (size_t)i * 256 + l * 4);
  float4 acc;
  acc.x = di * self.x; acc.y = di * self.y; acc.z = di * self.z; acc.w = di * self.w;
  const int e1 = rp[i + 1];
#pragma unroll 4
  for (int e = rp[i]; e < e1; e++) {
    int s = cs[e];
    float wgt = dinv[s];
    float4 rrow = ld_bf4(H + (size_t)s * 256 + l * 4);
    acc.x += wgt * rrow.x; acc.y += wgt * rrow.y; acc.z += wgt * rrow.z; acc.w += wgt * rrow.w;
  }
  float4 b = *(const float4*)(bias + l * 4);
  float4 o;
  o.x = fmaxf(di * acc.x + b.x, 0.f);
  o.y = fmaxf(di * acc.y + b.y, 0.f);
  o.z = fmaxf(di * acc.z + b.z, 0.f);
  o.w = fmaxf(di * acc.w + b.w, 0.f);
  *(float4*)(out + (size_t)i * 256 + l * 4) = o;
}

// 64-dim: 16 lanes/node (bf16x4 each), 16 nodes/block. BIAS=1 adds bias (h2), else raw (q2).
template <int BIAS>
__global__ __launch_bounds__(256) void prop64(const unsigned short* __restrict__ H,
                                              const int* __restrict__ rp,
                                              const int* __restrict__ cs,
                                              const float* __restrict__ dinv,
                                              const float* __restrict__ bias,
                                              unsigned short* __restrict__ out, int n) {
  const int i = blockIdx.x * 16 + (threadIdx.x >> 4);
  const int l = threadIdx.x & 15;
  if (i >= n) return;
  const float di = dinv[i];
  float4 self = ld_bf4(H + (size_t)i * 64 + l * 4);
  float4 acc;
  acc.x = di * self.x; acc.y = di * self.y; acc.z = di * self.z; acc.w = di * self.w;
  const int e1 = rp[i + 1];
#pragma unroll 4
  for (int e = rp[i]; e < e1; e++) {
    int s = cs[e];
    float wgt = dinv[s];
    float4 rrow = ld_bf4(H + (size_t)s * 64 + l * 4);
    acc.x += wgt * rrow.x; acc.y += wgt * rrow.y; acc.z += wgt * rrow.z; acc.w += wgt * rrow.w;
  }
  float4 o;
  o.x = di * acc.x; o.y = di * acc.y; o.z = di * acc.z; o.w = di * acc.w;
  if (BIAS) {
    float4 b = *(const float4*)(bias + l * 4);
    o.x += b.x; o.y += b.y; o.z += b.z; o.w += b.w;
  }
  ushort4 ob;
  ob.x = f2bf(o.x); ob.y = f2bf(o.y); ob.z = f2bf(o.z); ob.w = f2bf(o.w);
  *(ushort4*)(out + (size_t)i * 64 + l * 4) = ob;
}

// ---------------- fused tail: h = relu(h3+b21)+h1 ; out = h @ Wfc + bfc ----------------
__global__ __launch_bounds__(256) void final_k(const float* __restrict__ h1,
                                               const float* __restrict__ h3,
                                               const float* __restrict__ b21,
                                               const float* __restrict__ Wfc,
                                               const float* __restrict__ bfc,
                                               float* __restrict__ out, int M) {
  __shared__ float hs[16][260];
  __shared__ float wt[16][260];
  __shared__ float bs[16];
  const int t = threadIdx.x;
  for (int j = t; j < 4096; j += 256) { int k = j >> 4, c = j & 15; wt[c][k] = Wfc[j]; }
  if (t < 16) bs[t] = bfc[t];
  const float bb = b21[t];
  const int node0 = blockIdx.x * 16;
#pragma unroll
  for (int nl = 0; nl < 16; nl++) {
    int i = node0 + nl;
    float v = 0.f;
    if (i < M) {
      size_t o = (size_t)i * 256 + t;
      v = fmaxf(h3[o] + bb, 0.f) + h1[o];
    }
    hs[nl][t] = v;
  }
  __syncthreads();
  const int nl = t >> 4, c = t & 15;
  const int i = node0 + nl;
  if (i >= M) return;
  const float4* hp = (const float4*)&hs[nl][0];
  const float4* wp = (const float4*)&wt[c][0];
  float s = bs[c];
#pragma unroll 8
  for (int k4 = 0; k4 < 64; k4++) {
    float4 a = hp[k4], b = wp[k4];
    s += a.x * b.x + a.y * b.y + a.z * b.z + a.w * b.w;
  }
  out[(size_t)i * 16 + c] = s;
}

// ---------------- launch ----------------
extern "C" void kernel_launch(void* const* d_in, const int* in_sizes, int n_in,
                              void* d_out, int out_size, void* d_ws, size_t ws_size,
                              hipStream_t stream) {
  const float* X   = (const float*)d_in[0];
  const int*   ei1 = (const int*)d_in[1];
  const int*   ei2 = (const int*)d_in[2];
  const float* W10 = (const float*)d_in[3];
  const float* b10 = (const float*)d_in[4];
  const float* W20 = (const float*)d_in[5];
  const float* b20 = (const float*)d_in[6];
  const float* W21 = (const float*)d_in[7];
  const float* b21 = (const float*)d_in[8];
  const float* Wfc = (const float*)d_in[9];
  const float* bfc = (const float*)d_in[10];
  float* out = (float*)d_out;

  const int N = N_NODES;
  const int E1 = in_sizes[1] / 2, E2 = in_sizes[2] / 2;
  const int* src1 = ei1; const int* dst1 = ei1 + E1;
  const int* src2 = ei2; const int* dst2 = ei2 + E2;
  const int nch1 = (E1 + CHUNK - 1) / CHUNK, nch2 = (E2 + CHUNK - 1) / CHUNK;
  const int nchmax = (nch1 > nch2) ? nch1 : nch2;

  char* p = (char*)d_ws;
  auto alloc = [&](size_t b) { char* r = p; p += (b + 255) & ~(size_t)255; return (void*)r; };
  int* M1 = (int*)alloc((size_t)nch1 * NBKT * 4);
  int* M2 = (int*)alloc((size_t)nch2 * NBKT * 4);
  int* bases = (int*)alloc((size_t)2 * (NBKT + 1) * 4);
  unsigned* eb1 = (unsigned*)alloc((size_t)E1 * 4);
  unsigned* eb2 = (unsigned*)alloc((size_t)E2 * 4);
  int* rp1 = (int*)alloc((size_t)(N + 1) * 4);
  int* rp2 = (int*)alloc((size_t)(N + 1) * 4);
  float* dinv1 = (float*)alloc((size_t)N * 4);
  float* dinv2 = (float*)alloc((size_t)N * 4);
  int* csr1s = (int*)alloc((size_t)E1 * 4);
  int* csr2s = (int*)alloc((size_t)E2 * 4);
  unsigned short* WcatT = (unsigned short*)alloc(384 * 512 * 2);
  unsigned short* W21T  = (unsigned short*)alloc(256 * 64 * 2);
  unsigned short* Xb = (unsigned short*)alloc((size_t)N * 512 * 2);  // reused as h1 (N*256 f32)
  float* h1 = (float*)Xb;
  unsigned short* Xh1b = (unsigned short*)alloc((size_t)N * 256 * 2);  // bf16 GEMM1 out (256 cols)
  unsigned short* Xh2b = (unsigned short*)alloc((size_t)N * 64 * 2);   // bf16 GEMM1 out (64 cols)
  unsigned short* h2b  = (unsigned short*)alloc((size_t)N * 64 * 2);
  unsigned short* q2b  = (unsigned short*)alloc((size_t)N * 64 * 2);
  float* h3 = (float*)alloc((size_t)N * 256 * 4);

  // CSR build (no global atomics)
  binA<<<dim3(nchmax, 2), 256, 0, stream>>>(dst1, dst2, M1, M2, E1, E2, nch1, nch2);
  bin_offsets<<<dim3(2), 512, 0, stream>>>(M1, M2, bases, nch1, nch2, E1, E2);
  binB<<<dim3(nchmax, 2), 256, 0, stream>>>(src1, dst1, M1, eb1, E1, nch1,
                                            src2, dst2, M2, eb2, E2, nch2);
  binC<<<dim3(NBKT, 2), 256, 0, stream>>>(eb1, eb2, bases, rp1, dinv1, csr1s,
                                          rp2, dinv2, csr2s, N);
  cvt_x<<<dim3(4096), 256, 0, stream>>>((const float4*)X, (ushort4*)Xb, N * FDIM / 4);
  cvt_w<<<dim3((384 * 512 + 256 * 64 + 255) / 256), 256, 0, stream>>>(W10, W20, W21, WcatT, W21T);
  // Xh1b = bf16(x@W10), Xh2b = bf16(x@W20)  (fused x @ [W10|W20], N padded to 384)
  gemm_bt<512, 1><<<dim3((N + 127) / 128, 3), 256, 0, stream>>>(Xb, WcatT, Xh1b, Xh2b, N, 320);
  // h1 = relu(prop1(Xh1) + b10)  fp32 (overwrites Xb)
  prop256<<<dim3((N + 3) / 4), 256, 0, stream>>>(Xh1b, rp1, csr1s, dinv1, b10, h1, N);
  // h2 = prop2(Xh2) + b20  -> bf16
  prop64<1><<<dim3((N + 15) / 16), 256, 0, stream>>>(Xh2b, rp2, csr2s, dinv2, b20, h2b, N);
  // q2 = prop2(h2) -> bf16
  prop64<0><<<dim3((N + 15) / 16), 256, 0, stream>>>(h2b, rp2, csr2s, dinv2, nullptr, q2b, N);
  // h3 = q2 @ W21  fp32 (prop/transform commute)
  gemm_bt<64, 0><<<dim3((N + 127) / 128, 2), 256, 0, stream>>>(q2b, W21T, h3, nullptr, N, 256);
  // out = (relu(h3+b21)+h1) @ Wfc + bfc
  final_k<<<dim3((N + 15) / 16), 256, 0, stream>>>(h1, h3, b21, Wfc, bfc, out, N);
}